// Round 1
// baseline (383.544 us; speedup 1.0000x reference)
//
#include <hip/hip_runtime.h>

// Problem constants
#define BFULL 400
#define LROW  96      // query length L (= S, kv length)
#define CDIM  512     // channels
#define LC    (LROW*CDIM)   // 49152

// LDS layout constants
#define KC_LD 40      // bf16 per row of Kc   (80 B rows, 16B aligned, 20-bank stride)
#define S_LD  97      // f32 per row of Smat  (odd stride, conflict-free)
#define P_LD  104     // bf16 per row of P    (208 B rows, 16B aligned)
#define VT_LD 104     // bf16 per row of Vt
// regionA: max(Kc 96*40*2=7680, P 96*104*2=19968) = 19968
// regionB: max(S 96*97*4=37248, Vt 64*104*2=13312) = 37248
#define REGA  19968
#define LDSZ  (19968 + 37248)   // 57216 bytes

typedef __bf16 bf16;
typedef bf16  bf16x8 __attribute__((ext_vector_type(8)));
typedef float f32x4  __attribute__((ext_vector_type(4)));

#define MFMA16(a,b,c) __builtin_amdgcn_mfma_f32_16x16x32_bf16((a),(b),(c),0,0,0)

__device__ __forceinline__ bf16x8 cvt8(f32x4 a, f32x4 b) {
    bf16x8 v;
    v[0]=(bf16)a.x; v[1]=(bf16)a.y; v[2]=(bf16)a.z; v[3]=(bf16)a.w;
    v[4]=(bf16)b.x; v[5]=(bf16)b.y; v[6]=(bf16)b.z; v[7]=(bf16)b.w;
    return v;
}

// ---------------------------------------------------------------------------
// One workgroup (384 threads = 6 waves) computes one [96,512] attention:
//   O = softmax(q @ kv^T / sqrt(512)) @ kv
//   out[i] = outScale*O[i] + (add0?add0[i]:0) + (add1?add1[i]:0)
// Wave w owns output rows [16w, 16w+16).
// ---------------------------------------------------------------------------
__device__ __forceinline__ void attn_core(
    const float* __restrict__ q, const float* __restrict__ kv,
    float outScale,
    const float* __restrict__ add0, const float* __restrict__ add1,
    float* __restrict__ out, char* lds)
{
    const int tid  = threadIdx.x;
    const int wave = tid >> 6;
    const int lane = tid & 63;
    const int l16  = lane & 15;
    const int quad = lane >> 4;
    const int srow  = tid >> 2;   // 0..95 (staging / softmax row)
    const int spart = tid & 3;    // 0..3

    bf16*  Kc   = (bf16*)lds;            // [96][KC_LD]  (phase 1)
    bf16*  P    = (bf16*)lds;            // [96][P_LD]   (phase 2/3, aliases Kc)
    float* Smat = (float*)(lds + REGA);  // [96][S_LD]   (phase 1/2)
    bf16*  Vt   = (bf16*)(lds + REGA);   // [64][VT_LD]  (phase 3, aliases Smat)

    // ---- Phase 1: S = q @ kv^T * (1/sqrt(512)) -----------------------------
    f32x4 acc[6];
#pragma unroll
    for (int i = 0; i < 6; i++) acc[i] = {0.f, 0.f, 0.f, 0.f};

#pragma unroll 1
    for (int kb = 0; kb < CDIM; kb += 32) {
        // cooperative stage: Kc[r][0..31] <- bf16(kv[r][kb..kb+31]); 4 threads/row
        {
            const float* src = kv + srow*CDIM + kb + spart*8;
            f32x4 a = *(const f32x4*)src;
            f32x4 b = *(const f32x4*)(src + 4);
            *(bf16x8*)(Kc + srow*KC_LD + spart*8) = cvt8(a, b);
        }
        // A fragment straight from global: Q[16w+l16][kb+quad*8 .. +7]
        bf16x8 aq;
        {
            const float* srcq = q + (wave*16 + l16)*CDIM + kb + quad*8;
            f32x4 a = *(const f32x4*)srcq;
            f32x4 b = *(const f32x4*)(srcq + 4);
            aq = cvt8(a, b);
        }
        __syncthreads();
#pragma unroll
        for (int ct = 0; ct < 6; ct++) {
            bf16x8 bk = *(const bf16x8*)(Kc + (ct*16 + l16)*KC_LD + quad*8);
            acc[ct] = MFMA16(aq, bk, acc[ct]);
        }
        __syncthreads();
    }

    // write scaled scores to LDS; D layout: col=lane&15, row=quad*4+reg
    const float rs = 0.04419417382415922f;   // 1/sqrt(512)
#pragma unroll
    for (int ct = 0; ct < 6; ct++)
#pragma unroll
        for (int r = 0; r < 4; r++)
            Smat[(wave*16 + quad*4 + r)*S_LD + ct*16 + l16] = acc[ct][r] * rs;
    __syncthreads();

    // ---- Phase 2: softmax rows; P = bf16(softmax(S)) -----------------------
    {
        const float* Srow = Smat + srow*S_LD + spart*24;
        float mx = -1e30f;
#pragma unroll
        for (int j = 0; j < 24; j++) mx = fmaxf(mx, Srow[j]);
        mx = fmaxf(mx, __shfl_xor(mx, 1));
        mx = fmaxf(mx, __shfl_xor(mx, 2));
        float e[24], sum = 0.f;
#pragma unroll
        for (int j = 0; j < 24; j++) { e[j] = __expf(Srow[j] - mx); sum += e[j]; }
        sum += __shfl_xor(sum, 1);
        sum += __shfl_xor(sum, 2);
        const float inv = 1.f / sum;
        bf16* Prow = P + srow*P_LD + spart*24;   // P aliases dead Kc, not Smat
#pragma unroll
        for (int j = 0; j < 24; j++) Prow[j] = (bf16)(e[j] * inv);
    }
    __syncthreads();

    // ---- Phase 3: O = P @ V, 64-column chunks ------------------------------
#pragma unroll 1
    for (int nb = 0; nb < CDIM/64; nb++) {
        const int nbase = nb*64;
        // stage Vt[c][s] = bf16(kv[s][nbase+c]); thread: row s=srow, cols spart*16..+15
        {
            const float* src = kv + srow*CDIM + nbase + spart*16;
#pragma unroll
            for (int j = 0; j < 16; j++)
                Vt[(spart*16 + j)*VT_LD + srow] = (bf16)src[j];
        }
        __syncthreads();

        f32x4 oacc[4];
#pragma unroll
        for (int i = 0; i < 4; i++) oacc[i] = {0.f, 0.f, 0.f, 0.f};
#pragma unroll
        for (int sb = 0; sb < 96; sb += 32) {
            bf16x8 ap = *(const bf16x8*)(P + (wave*16 + l16)*P_LD + sb + quad*8);
#pragma unroll
            for (int ct = 0; ct < 4; ct++) {
                bf16x8 bv = *(const bf16x8*)(Vt + (ct*16 + l16)*VT_LD + sb + quad*8);
                oacc[ct] = MFMA16(ap, bv, oacc[ct]);
            }
        }
        // epilogue: fused scale + optional adds, coalesced 16-lane stores
        const int orow0 = wave*16 + quad*4;
#pragma unroll
        for (int ct = 0; ct < 4; ct++) {
            const int col = nbase + ct*16 + l16;
#pragma unroll
            for (int r = 0; r < 4; r++) {
                const int idx = (orow0 + r)*CDIM + col;
                float v = oacc[ct][r] * outScale;
                if (add0) v += add0[idx];
                if (add1) v += add1[idx];
                out[idx] = v;
            }
        }
        __syncthreads();   // protect Vt before next chunk's staging
    }
}

// ---------------------------------------------------------------------------
// Kernel 1: hierarchical means. One thread per (g, l*c); g in [0,16).
// m1*[g*5+q] = mean of 5, m0*[g] = mean of 25.
// ---------------------------------------------------------------------------
__global__ __launch_bounds__(256) void means_kernel(
    const float* __restrict__ x, const float* __restrict__ cr,
    float* __restrict__ m1x, float* __restrict__ m1c,
    float* __restrict__ m0x, float* __restrict__ m0c)
{
    const int idx = blockIdx.x*256 + threadIdx.x;   // 16*49152 total
    const int g  = idx / LC;
    const int lc = idx - g*LC;
    const float* xb = x  + (size_t)(g*25)*LC + lc;
    const float* cb = cr + (size_t)(g*25)*LC + lc;
    float ax = 0.f, ac = 0.f;
#pragma unroll
    for (int qq = 0; qq < 5; qq++) {
        float sx = 0.f, sc = 0.f;
#pragma unroll
        for (int j = 0; j < 5; j++) {
            sx += xb[(size_t)(qq*5 + j)*LC];
            sc += cb[(size_t)(qq*5 + j)*LC];
        }
        m1x[(size_t)(g*5 + qq)*LC + lc] = sx * 0.2f;
        m1c[(size_t)(g*5 + qq)*LC + lc] = sc * 0.2f;
        ax += sx; ac += sc;
    }
    m0x[(size_t)g*LC + lc] = ax * 0.04f;
    m0c[(size_t)g*LC + lc] = ac * 0.04f;
}

// ---------------------------------------------------------------------------
// Kernel 2: 96 pooled attentions -> ws (pre-scaled by 1/3)
// ---------------------------------------------------------------------------
__global__ __launch_bounds__(384) void attn_levels_kernel(
    const float* __restrict__ m1x, const float* __restrict__ m1c,
    const float* __restrict__ m0x, const float* __restrict__ m0c,
    float* __restrict__ lvl1s, float* __restrict__ lvl0s)
{
    __shared__ char lds[LDSZ];
    const int j = blockIdx.x;
    const float *q, *kv; float* o;
    if (j < 80) { q = m1x + (size_t)j*LC; kv = m1c + (size_t)j*LC; o = lvl1s + (size_t)j*LC; }
    else { const int g = j - 80; q = m0x + (size_t)g*LC; kv = m0c + (size_t)g*LC; o = lvl0s + (size_t)g*LC; }
    attn_core(q, kv, 1.f/3.f, nullptr, nullptr, o, lds);
}

// ---------------------------------------------------------------------------
// Kernel 3: 400 full attentions, fused with level gather: out = 4/3*attn + lvl0 + lvl1
// ---------------------------------------------------------------------------
__global__ __launch_bounds__(384) void attn_full_kernel(
    const float* __restrict__ x, const float* __restrict__ cr,
    const float* __restrict__ lvl0s, const float* __restrict__ lvl1s,
    float* __restrict__ out)
{
    __shared__ char lds[LDSZ];
    const int b = blockIdx.x;
    attn_core(x + (size_t)b*LC, cr + (size_t)b*LC, 4.f/3.f,
              lvl0s + (size_t)(b/25)*LC, lvl1s + (size_t)(b/5)*LC,
              out + (size_t)b*LC, lds);
}

extern "C" void kernel_launch(void* const* d_in, const int* in_sizes, int n_in,
                              void* d_out, int out_size, void* d_ws, size_t ws_size,
                              hipStream_t stream)
{
    const float* x  = (const float*)d_in[0];
    const float* cr = (const float*)d_in[1];
    float* out = (float*)d_out;
    float* ws  = (float*)d_ws;

    // ws layout (floats): m1x[80*LC] m1c[80*LC] m0x[16*LC] m0c[16*LC] lvl1s[80*LC] lvl0s[16*LC]
    // total = 288*LC floats = 56,623,104 bytes
    float* m1x   = ws;
    float* m1c   = m1x   + (size_t)80*LC;
    float* m0x   = m1c   + (size_t)80*LC;
    float* m0c   = m0x   + (size_t)16*LC;
    float* lvl1s = m0c   + (size_t)16*LC;
    float* lvl0s = lvl1s + (size_t)80*LC;

    means_kernel<<<dim3((16*LC)/256), dim3(256), 0, stream>>>(x, cr, m1x, m1c, m0x, m0c);
    attn_levels_kernel<<<dim3(96), dim3(384), 0, stream>>>(m1x, m1c, m0x, m0c, lvl1s, lvl0s);
    attn_full_kernel<<<dim3(400), dim3(384), 0, stream>>>(x, cr, lvl0s, lvl1s, out);
}

// Round 2
// 295.742 us; speedup vs baseline: 1.2969x; 1.2969x over previous
//
#include <hip/hip_runtime.h>

// Problem constants
#define LROW  96      // query length L (= S, kv length)
#define CDIM  512     // channels
#define LC    (LROW*CDIM)   // 49152

// LDS layout
#define KC_LD 136     // bf16 stride of Kc rows: 128-col chunk + 8 pad
#define S_LD  97      // f32 stride of score rows
#define P_LD  104     // bf16 stride of P rows
#define VT_LD 104     // bf16 stride of Vt rows
#define REGA  26112   // max(Kc 96*136*2=26112, P 96*104*2=19968)
#define REGB  37248   // max(Smat 96*97*4=37248, Vt 128*104*2=26624)
#define LDSZ  (REGA + REGB)   // 63360 B -> 2 blocks/CU

typedef __bf16 bf16;
typedef bf16  bf16x2 __attribute__((ext_vector_type(2)));
typedef bf16  bf16x8 __attribute__((ext_vector_type(8)));
typedef float f32x4  __attribute__((ext_vector_type(4)));

#define MFMA16(a,b,c) __builtin_amdgcn_mfma_f32_16x16x32_bf16((a),(b),(c),0,0,0)

__device__ __forceinline__ bf16x8 cvt8(f32x4 a, f32x4 b) {
    bf16x8 v;
    v[0]=(bf16)a.x; v[1]=(bf16)a.y; v[2]=(bf16)a.z; v[3]=(bf16)a.w;
    v[4]=(bf16)b.x; v[5]=(bf16)b.y; v[6]=(bf16)b.z; v[7]=(bf16)b.w;
    return v;
}

// ---------------------------------------------------------------------------
// One workgroup (384 threads = 6 waves) computes one [96,512] attention:
//   O = softmax(q @ kv^T / sqrt(512)) @ kv
//   out = outScale*O + (HASADD ? add0 + add1 : 0)
// Software-pipelined: global loads for chunk c+1 issue before chunk c's barrier.
// ---------------------------------------------------------------------------
template<bool HASADD>
__device__ __forceinline__ void attn_core(
    const float* __restrict__ q, const float* __restrict__ kv,
    float outScale,
    const float* __restrict__ add0, const float* __restrict__ add1,
    float* __restrict__ out, char* lds)
{
    const int tid  = threadIdx.x;
    const int wave = tid >> 6;
    const int lane = tid & 63;
    const int l16  = lane & 15;
    const int quad = lane >> 4;
    const int srow = tid >> 2;   // 0..95 (stage/softmax row)
    const int spart = tid & 3;   // 0..3

    bf16*  Kc   = (bf16*)lds;            // [96][KC_LD]  phase 1
    bf16*  P    = (bf16*)lds;            // [96][P_LD]   phase 2/3 (aliases Kc)
    float* Smat = (float*)(lds + REGA);  // [96][S_LD]   phase 1/2
    bf16*  Vt   = (bf16*)(lds + REGA);   // [128][VT_LD] phase 3 (aliases Smat)

    // ---- Phase 1: S = q @ kv^T * (1/sqrt(512)); 4 chunks of 128 cols -------
    f32x4 acc[6];
#pragma unroll
    for (int i = 0; i < 6; i++) acc[i] = {0.f, 0.f, 0.f, 0.f};

    const float* kvst = kv + srow*CDIM + spart*32;          // staging base
    const float* qrow = q + (wave*16 + l16)*CDIM + quad*8;  // A-frag base

    f32x4 sbuf[8], qbuf[8];
    // prefetch chunk 0
#pragma unroll
    for (int i = 0; i < 8; i++) sbuf[i] = *(const f32x4*)(kvst + i*4);
#pragma unroll
    for (int ks = 0; ks < 4; ks++) {
        qbuf[2*ks]   = *(const f32x4*)(qrow + ks*32);
        qbuf[2*ks+1] = *(const f32x4*)(qrow + ks*32 + 4);
    }

#pragma unroll
    for (int c = 0; c < 4; c++) {
        // consume qbuf -> bf16 A-frags (frees qbuf)
        bf16x8 af[4];
#pragma unroll
        for (int ks = 0; ks < 4; ks++) af[ks] = cvt8(qbuf[2*ks], qbuf[2*ks+1]);
        // consume sbuf -> LDS (frees sbuf)
        bf16* kdst = Kc + srow*KC_LD + spart*32;
#pragma unroll
        for (int i = 0; i < 4; i++)
            *(bf16x8*)(kdst + i*8) = cvt8(sbuf[2*i], sbuf[2*i+1]);
        // prefetch chunk c+1 (latency hidden across barrier + MFMA)
        if (c < 3) {
            const int cb = (c+1)*128;
#pragma unroll
            for (int i = 0; i < 8; i++) sbuf[i] = *(const f32x4*)(kvst + cb + i*4);
#pragma unroll
            for (int ks = 0; ks < 4; ks++) {
                qbuf[2*ks]   = *(const f32x4*)(qrow + cb + ks*32);
                qbuf[2*ks+1] = *(const f32x4*)(qrow + cb + ks*32 + 4);
            }
        }
        __syncthreads();
#pragma unroll
        for (int ks = 0; ks < 4; ks++) {
#pragma unroll
            for (int ct = 0; ct < 6; ct++) {
                bf16x8 bk = *(const bf16x8*)(Kc + (ct*16 + l16)*KC_LD + ks*32 + quad*8);
                acc[ct] = MFMA16(af[ks], bk, acc[ct]);
            }
        }
        __syncthreads();
    }

    // scaled scores -> LDS; C/D layout: col=lane&15, row=quad*4+reg
    const float rs = 0.04419417382415922f;   // 1/sqrt(512)
#pragma unroll
    for (int ct = 0; ct < 6; ct++)
#pragma unroll
        for (int r = 0; r < 4; r++)
            Smat[(wave*16 + quad*4 + r)*S_LD + ct*16 + l16] = acc[ct][r] * rs;

    // prefetch phase-3 V chunk 0 while scores settle
    const int rp = tid % 48;          // row pair
    const int cg = tid / 48;          // col group (16 cols)
    const float* v0 = kv + (2*rp)*CDIM + cg*16;
    const float* v1 = v0 + CDIM;
    f32x4 vbuf[8];
#pragma unroll
    for (int i = 0; i < 4; i++) {
        vbuf[i]   = *(const f32x4*)(v0 + i*4);
        vbuf[4+i] = *(const f32x4*)(v1 + i*4);
    }
    __syncthreads();

    // ---- Phase 2: softmax rows; P = bf16(softmax(S)) -----------------------
    {
        const float* Srow = Smat + srow*S_LD + spart*24;
        float mx = -1e30f;
#pragma unroll
        for (int j = 0; j < 24; j++) mx = fmaxf(mx, Srow[j]);
        mx = fmaxf(mx, __shfl_xor(mx, 1));
        mx = fmaxf(mx, __shfl_xor(mx, 2));
        float e[24], sum = 0.f;
#pragma unroll
        for (int j = 0; j < 24; j++) { e[j] = __expf(Srow[j] - mx); sum += e[j]; }
        sum += __shfl_xor(sum, 1);
        sum += __shfl_xor(sum, 2);
        const float inv = 1.f / sum;
        bf16* Prow = P + srow*P_LD + spart*24;   // P aliases dead Kc
#pragma unroll
        for (int j = 0; j < 24; j++) Prow[j] = (bf16)(e[j] * inv);
    }
    __syncthreads();

    // ---- Phase 3: O = P @ V; 4 chunks of 128 cols --------------------------
#pragma unroll
    for (int nb = 0; nb < 4; nb++) {
        // transpose-stage Vt[c][s] (paired-row b32 writes), frees vbuf
        bf16* vdst = Vt + cg*16*VT_LD + 2*rp;
#pragma unroll
        for (int j = 0; j < 16; j++) {
            float f0 = vbuf[j >> 2][j & 3];
            float f1 = vbuf[4 + (j >> 2)][j & 3];
            bf16x2 pr; pr[0] = (bf16)f0; pr[1] = (bf16)f1;
            *(bf16x2*)(vdst + j*VT_LD) = pr;
        }
        // prefetch next V chunk
        if (nb < 3) {
            const int cb = (nb+1)*128;
#pragma unroll
            for (int i = 0; i < 4; i++) {
                vbuf[i]   = *(const f32x4*)(v0 + cb + i*4);
                vbuf[4+i] = *(const f32x4*)(v1 + cb + i*4);
            }
        }
        __syncthreads();

        f32x4 oacc[8];
#pragma unroll
        for (int i = 0; i < 8; i++) oacc[i] = {0.f, 0.f, 0.f, 0.f};
#pragma unroll
        for (int sb = 0; sb < 96; sb += 32) {
            bf16x8 ap = *(const bf16x8*)(P + (wave*16 + l16)*P_LD + sb + quad*8);
#pragma unroll
            for (int ct = 0; ct < 8; ct++) {
                bf16x8 bv = *(const bf16x8*)(Vt + (ct*16 + l16)*VT_LD + sb + quad*8);
                oacc[ct] = MFMA16(ap, bv, oacc[ct]);
            }
        }
        __syncthreads();   // Vt consumed; next iter may restage

        // epilogue: fused scale + adds, coalesced stores
        const int orow0 = wave*16 + quad*4;
#pragma unroll
        for (int ct = 0; ct < 8; ct++) {
            const int col = nb*128 + ct*16 + l16;
#pragma unroll
            for (int r = 0; r < 4; r++) {
                const int idx = (orow0 + r)*CDIM + col;
                float v = oacc[ct][r] * outScale;
                if (HASADD) v += add0[idx] + add1[idx];
                out[idx] = v;
            }
        }
    }
}

// ---------------------------------------------------------------------------
// Kernel 1: hierarchical means
// ---------------------------------------------------------------------------
__global__ __launch_bounds__(256) void means_kernel(
    const float* __restrict__ x, const float* __restrict__ cr,
    float* __restrict__ m1x, float* __restrict__ m1c,
    float* __restrict__ m0x, float* __restrict__ m0c)
{
    const int idx = blockIdx.x*256 + threadIdx.x;   // 16*LC total
    const int g  = idx / LC;
    const int lc = idx - g*LC;
    const float* xb = x  + (size_t)(g*25)*LC + lc;
    const float* cb = cr + (size_t)(g*25)*LC + lc;
    float ax = 0.f, ac = 0.f;
#pragma unroll
    for (int qq = 0; qq < 5; qq++) {
        float sx = 0.f, sc = 0.f;
#pragma unroll
        for (int j = 0; j < 5; j++) {
            sx += xb[(size_t)(qq*5 + j)*LC];
            sc += cb[(size_t)(qq*5 + j)*LC];
        }
        m1x[(size_t)(g*5 + qq)*LC + lc] = sx * 0.2f;
        m1c[(size_t)(g*5 + qq)*LC + lc] = sc * 0.2f;
        ax += sx; ac += sc;
    }
    m0x[(size_t)g*LC + lc] = ax * 0.04f;
    m0c[(size_t)g*LC + lc] = ac * 0.04f;
}

// ---------------------------------------------------------------------------
// Kernel 2: 96 pooled attentions -> ws (pre-scaled by 1/3)
// ---------------------------------------------------------------------------
__global__ __launch_bounds__(384, 3) void attn_levels_kernel(
    const float* __restrict__ m1x, const float* __restrict__ m1c,
    const float* __restrict__ m0x, const float* __restrict__ m0c,
    float* __restrict__ lvl1s, float* __restrict__ lvl0s)
{
    __shared__ char lds[LDSZ];
    const int j = blockIdx.x;
    const float *q, *kv; float* o;
    if (j < 80) { q = m1x + (size_t)j*LC; kv = m1c + (size_t)j*LC; o = lvl1s + (size_t)j*LC; }
    else { const int g = j - 80; q = m0x + (size_t)g*LC; kv = m0c + (size_t)g*LC; o = lvl0s + (size_t)g*LC; }
    attn_core<false>(q, kv, 1.f/3.f, nullptr, nullptr, o, lds);
}

// ---------------------------------------------------------------------------
// Kernel 3: 400 full attentions, fused: out = 4/3*attn + lvl0 + lvl1
// ---------------------------------------------------------------------------
__global__ __launch_bounds__(384, 3) void attn_full_kernel(
    const float* __restrict__ x, const float* __restrict__ cr,
    const float* __restrict__ lvl0s, const float* __restrict__ lvl1s,
    float* __restrict__ out)
{
    __shared__ char lds[LDSZ];
    const int b = blockIdx.x;
    attn_core<true>(x + (size_t)b*LC, cr + (size_t)b*LC, 4.f/3.f,
                    lvl0s + (size_t)(b/25)*LC, lvl1s + (size_t)(b/5)*LC,
                    out + (size_t)b*LC, lds);
}

extern "C" void kernel_launch(void* const* d_in, const int* in_sizes, int n_in,
                              void* d_out, int out_size, void* d_ws, size_t ws_size,
                              hipStream_t stream)
{
    const float* x  = (const float*)d_in[0];
    const float* cr = (const float*)d_in[1];
    float* out = (float*)d_out;
    float* ws  = (float*)d_ws;

    // ws layout (floats): m1x[80*LC] m1c[80*LC] m0x[16*LC] m0c[16*LC] lvl1s[80*LC] lvl0s[16*LC]
    float* m1x   = ws;
    float* m1c   = m1x   + (size_t)80*LC;
    float* m0x   = m1c   + (size_t)80*LC;
    float* m0c   = m0x   + (size_t)16*LC;
    float* lvl1s = m0c   + (size_t)16*LC;
    float* lvl0s = lvl1s + (size_t)80*LC;

    means_kernel<<<dim3((16*LC)/256), dim3(256), 0, stream>>>(x, cr, m1x, m1c, m0x, m0c);
    attn_levels_kernel<<<dim3(96), dim3(384), 0, stream>>>(m1x, m1c, m0x, m0c, lvl1s, lvl0s);
    attn_full_kernel<<<dim3(400), dim3(384), 0, stream>>>(x, cr, lvl0s, lvl1s, out);
}

// Round 3
// 260.588 us; speedup vs baseline: 1.4718x; 1.1349x over previous
//
#include <hip/hip_runtime.h>

// Problem constants
#define LROW  96      // query length L (= S, kv length)
#define CDIM  512     // channels
#define LC    (LROW*CDIM)   // 49152

// LDS layout
#define KC_LD 136     // bf16 stride of Kc rows: 128-col chunk + 8 pad
#define S_LD  97      // f32 stride of score rows
#define P_LD  104     // bf16 stride of P rows
#define VT_LD 104     // bf16 stride of Vt rows
#define REGA  26112   // max(Kc 96*136*2=26112, P 96*104*2=19968)
#define REGB  37248   // max(Smat 96*97*4=37248, Vt 128*104*2=26624)
#define LDSZ  (REGA + REGB)   // 63360 B -> 2 blocks/CU

typedef __bf16 bf16;
typedef bf16  bf16x2 __attribute__((ext_vector_type(2)));
typedef bf16  bf16x8 __attribute__((ext_vector_type(8)));
typedef float f32x4  __attribute__((ext_vector_type(4)));

#define MFMA16(a,b,c) __builtin_amdgcn_mfma_f32_16x16x32_bf16((a),(b),(c),0,0,0)

__device__ __forceinline__ bf16x8 cvt8(f32x4 a, f32x4 b) {
    bf16x8 v;
    v[0]=(bf16)a.x; v[1]=(bf16)a.y; v[2]=(bf16)a.z; v[3]=(bf16)a.w;
    v[4]=(bf16)b.x; v[5]=(bf16)b.y; v[6]=(bf16)b.z; v[7]=(bf16)b.w;
    return v;
}
__device__ __forceinline__ bf16x8 load8(const float* p) {
    f32x4 a = *(const f32x4*)p, b = *(const f32x4*)(p + 4);
    return cvt8(a, b);
}
__device__ __forceinline__ bf16x8 load8(const bf16* p) {
    return *(const bf16x8*)p;
}

// ---------------------------------------------------------------------------
// One workgroup (384 threads = 6 waves) computes one [96,512] attention:
//   O = softmax(q @ kv^T / sqrt(512)) @ kv
//   FULL:  out(f32) = outScale*O + add0 + add1     (adds bf16)
//   !FULL: out(bf16) = outScale*O
// Software-pipelined: global loads for chunk c+1 issue before chunk c's barrier.
// ---------------------------------------------------------------------------
template<bool FULL, typename TIN>
__device__ __forceinline__ void attn_core(
    const TIN* __restrict__ q, const TIN* __restrict__ kv,
    float outScale,
    const bf16* __restrict__ add0, const bf16* __restrict__ add1,
    void* __restrict__ outp, char* lds)
{
    const int tid  = threadIdx.x;
    const int wave = tid >> 6;
    const int lane = tid & 63;
    const int l16  = lane & 15;
    const int quad = lane >> 4;
    const int srow = tid >> 2;   // 0..95 (stage/softmax row)
    const int spart = tid & 3;   // 0..3

    bf16*  Kc   = (bf16*)lds;            // [96][KC_LD]  phase 1
    bf16*  P    = (bf16*)lds;            // [96][P_LD]   phase 2/3 (aliases Kc)
    float* Smat = (float*)(lds + REGA);  // [96][S_LD]   phase 1/2
    bf16*  Vt   = (bf16*)(lds + REGA);   // [128][VT_LD] phase 3 (aliases Smat)

    // ---- Phase 1: S = q @ kv^T * (1/sqrt(512)); 4 chunks of 128 cols -------
    f32x4 acc[6];
#pragma unroll
    for (int i = 0; i < 6; i++) acc[i] = {0.f, 0.f, 0.f, 0.f};

    const TIN* kvst = kv + srow*CDIM + spart*32;          // staging base
    const TIN* qrow = q + (wave*16 + l16)*CDIM + quad*8;  // A-frag base

    bf16x8 kbuf[4], qbuf[4];
    // prefetch chunk 0
#pragma unroll
    for (int i = 0; i < 4; i++) kbuf[i] = load8(kvst + i*8);
#pragma unroll
    for (int ks = 0; ks < 4; ks++) qbuf[ks] = load8(qrow + ks*32);

#pragma unroll
    for (int c = 0; c < 4; c++) {
        // consume: A-frags + K staging to LDS
        bf16x8 af[4];
#pragma unroll
        for (int ks = 0; ks < 4; ks++) af[ks] = qbuf[ks];
        bf16* kdst = Kc + srow*KC_LD + spart*32;
#pragma unroll
        for (int i = 0; i < 4; i++) *(bf16x8*)(kdst + i*8) = kbuf[i];
        // prefetch chunk c+1 (latency hidden across barrier + MFMA)
        if (c < 3) {
            const int cb = (c+1)*128;
#pragma unroll
            for (int i = 0; i < 4; i++) kbuf[i] = load8(kvst + cb + i*8);
#pragma unroll
            for (int ks = 0; ks < 4; ks++) qbuf[ks] = load8(qrow + cb + ks*32);
        }
        __syncthreads();
#pragma unroll
        for (int ks = 0; ks < 4; ks++) {
#pragma unroll
            for (int ct = 0; ct < 6; ct++) {
                bf16x8 bk = *(const bf16x8*)(Kc + (ct*16 + l16)*KC_LD + ks*32 + quad*8);
                acc[ct] = MFMA16(af[ks], bk, acc[ct]);
            }
        }
        __syncthreads();
    }

    // scaled scores -> LDS; C/D layout: col=lane&15, row=quad*4+reg
    const float rs = 0.04419417382415922f;   // 1/sqrt(512)
#pragma unroll
    for (int ct = 0; ct < 6; ct++)
#pragma unroll
        for (int r = 0; r < 4; r++)
            Smat[(wave*16 + quad*4 + r)*S_LD + ct*16 + l16] = acc[ct][r] * rs;

    // prefetch phase-3 V chunk 0 while scores settle
    const int rp = tid % 48;          // row pair: rows 2rp, 2rp+1
    const int cg = tid / 48;          // col group (16 cols)
    const TIN* v0 = kv + (2*rp)*CDIM + cg*16;
    bf16x8 vbuf[4];
    vbuf[0] = load8(v0);          vbuf[1] = load8(v0 + 8);
    vbuf[2] = load8(v0 + CDIM);   vbuf[3] = load8(v0 + CDIM + 8);
    __syncthreads();

    // ---- Phase 2: softmax rows; P = bf16(softmax(S)) -----------------------
    {
        const float* Srow = Smat + srow*S_LD + spart*24;
        float mx = -1e30f;
#pragma unroll
        for (int j = 0; j < 24; j++) mx = fmaxf(mx, Srow[j]);
        mx = fmaxf(mx, __shfl_xor(mx, 1));
        mx = fmaxf(mx, __shfl_xor(mx, 2));
        float e[24], sum = 0.f;
#pragma unroll
        for (int j = 0; j < 24; j++) { e[j] = __expf(Srow[j] - mx); sum += e[j]; }
        sum += __shfl_xor(sum, 1);
        sum += __shfl_xor(sum, 2);
        const float inv = 1.f / sum;
        bf16* Prow = P + srow*P_LD + spart*24;   // P aliases dead Kc
#pragma unroll
        for (int j = 0; j < 24; j++) Prow[j] = (bf16)(e[j] * inv);
    }
    __syncthreads();

    // ---- Phase 3: O = P @ V; 4 chunks of 128 cols --------------------------
#pragma unroll
    for (int nb = 0; nb < 4; nb++) {
        // transpose-stage Vt[c][s] (paired-row b32 writes), frees vbuf
        bf16* vdst = Vt + cg*16*VT_LD + 2*rp;
#pragma unroll
        for (int j = 0; j < 16; j++) {
            bf16x2 pr;
            pr[0] = vbuf[j >> 3][j & 7];
            pr[1] = vbuf[2 + (j >> 3)][j & 7];
            *(bf16x2*)(vdst + j*VT_LD) = pr;
        }
        // prefetch next V chunk
        if (nb < 3) {
            const int cb = (nb+1)*128;
            vbuf[0] = load8(v0 + cb);        vbuf[1] = load8(v0 + cb + 8);
            vbuf[2] = load8(v0 + cb + CDIM); vbuf[3] = load8(v0 + cb + CDIM + 8);
        }
        __syncthreads();

        f32x4 oacc[8];
#pragma unroll
        for (int i = 0; i < 8; i++) oacc[i] = {0.f, 0.f, 0.f, 0.f};
#pragma unroll
        for (int sb = 0; sb < 96; sb += 32) {
            bf16x8 ap = *(const bf16x8*)(P + (wave*16 + l16)*P_LD + sb + quad*8);
#pragma unroll
            for (int ct = 0; ct < 8; ct++) {
                bf16x8 bv = *(const bf16x8*)(Vt + (ct*16 + l16)*VT_LD + sb + quad*8);
                oacc[ct] = MFMA16(ap, bv, oacc[ct]);
            }
        }
        __syncthreads();   // Vt consumed; next iter restages

        // epilogue
        const int orow0 = wave*16 + quad*4;
#pragma unroll
        for (int ct = 0; ct < 8; ct++) {
            const int col = nb*128 + ct*16 + l16;
#pragma unroll
            for (int r = 0; r < 4; r++) {
                const int idx = (orow0 + r)*CDIM + col;
                float v = oacc[ct][r] * outScale;
                if constexpr (FULL) {
                    v += (float)add0[idx] + (float)add1[idx];
                    ((float*)outp)[idx] = v;
                } else {
                    ((bf16*)outp)[idx] = (bf16)v;
                }
            }
        }
    }
}

// ---------------------------------------------------------------------------
// Kernel 1: hierarchical means (bf16 outputs) + optional bf16 input copies
// ---------------------------------------------------------------------------
template<bool COPY>
__global__ __launch_bounds__(256) void means_kernel(
    const float* __restrict__ x, const float* __restrict__ cr,
    bf16* __restrict__ m1x, bf16* __restrict__ m1c,
    bf16* __restrict__ m0x, bf16* __restrict__ m0c,
    bf16* __restrict__ xb, bf16* __restrict__ cb)
{
    const int idx = blockIdx.x*256 + threadIdx.x;   // 16*LC total
    const int g  = idx / LC;
    const int lc = idx - g*LC;
    const float* xp = x  + (size_t)(g*25)*LC + lc;
    const float* cp = cr + (size_t)(g*25)*LC + lc;
    float ax = 0.f, ac = 0.f;
#pragma unroll
    for (int qq = 0; qq < 5; qq++) {
        float sx = 0.f, sc = 0.f;
#pragma unroll
        for (int j = 0; j < 5; j++) {
            const size_t b = (size_t)(qq*5 + j)*LC;
            float xv = xp[b], cv = cp[b];
            if (COPY) {
                xb[(size_t)(g*25 + qq*5 + j)*LC + lc] = (bf16)xv;
                cb[(size_t)(g*25 + qq*5 + j)*LC + lc] = (bf16)cv;
            }
            sx += xv; sc += cv;
        }
        m1x[(size_t)(g*5 + qq)*LC + lc] = (bf16)(sx * 0.2f);
        m1c[(size_t)(g*5 + qq)*LC + lc] = (bf16)(sc * 0.2f);
        ax += sx; ac += sc;
    }
    m0x[(size_t)g*LC + lc] = (bf16)(ax * 0.04f);
    m0c[(size_t)g*LC + lc] = (bf16)(ac * 0.04f);
}

// ---------------------------------------------------------------------------
// Kernel 2: 96 pooled attentions -> bf16 ws (pre-scaled by 1/3)
// ---------------------------------------------------------------------------
__global__ __launch_bounds__(384, 3) void attn_levels_kernel(
    const bf16* __restrict__ m1x, const bf16* __restrict__ m1c,
    const bf16* __restrict__ m0x, const bf16* __restrict__ m0c,
    bf16* __restrict__ lvl1s, bf16* __restrict__ lvl0s)
{
    __shared__ char lds[LDSZ];
    const int j = blockIdx.x;
    const bf16 *q, *kv; bf16* o;
    if (j < 80) { q = m1x + (size_t)j*LC; kv = m1c + (size_t)j*LC; o = lvl1s + (size_t)j*LC; }
    else { const int g = j - 80; q = m0x + (size_t)g*LC; kv = m0c + (size_t)g*LC; o = lvl0s + (size_t)g*LC; }
    attn_core<false, bf16>(q, kv, 1.f/3.f, nullptr, nullptr, o, lds);
}

// ---------------------------------------------------------------------------
// Kernel 3: 400 full attentions: out = 4/3*attn + lvl0 + lvl1
// ---------------------------------------------------------------------------
template<typename TIN>
__global__ __launch_bounds__(384, 3) void attn_full_kernel(
    const TIN* __restrict__ x, const TIN* __restrict__ cr,
    const bf16* __restrict__ lvl0s, const bf16* __restrict__ lvl1s,
    float* __restrict__ out)
{
    __shared__ char lds[LDSZ];
    const int b = blockIdx.x;
    attn_core<true, TIN>(x + (size_t)b*LC, cr + (size_t)b*LC, 4.f/3.f,
                         lvl0s + (size_t)(b/25)*LC, lvl1s + (size_t)(b/5)*LC,
                         out + (size_t)b*LC, lds);
}

extern "C" void kernel_launch(void* const* d_in, const int* in_sizes, int n_in,
                              void* d_out, int out_size, void* d_ws, size_t ws_size,
                              hipStream_t stream)
{
    const float* x  = (const float*)d_in[0];
    const float* cr = (const float*)d_in[1];
    float* out = (float*)d_out;
    bf16* ws = (bf16*)d_ws;

    // ws layout (bf16 elems):
    //   m1x[80*LC] m1c[80*LC] m0x[16*LC] m0c[16*LC] lvl1s[80*LC] lvl0s[16*LC]  (= 288*LC)
    //   [optional] xb[400*LC] cb[400*LC]                                        (+ 800*LC)
    bf16* m1x   = ws;
    bf16* m1c   = m1x   + (size_t)80*LC;
    bf16* m0x   = m1c   + (size_t)80*LC;
    bf16* m0c   = m0x   + (size_t)16*LC;
    bf16* lvl1s = m0c   + (size_t)16*LC;
    bf16* lvl0s = lvl1s + (size_t)80*LC;
    bf16* xb    = lvl0s + (size_t)16*LC;
    bf16* cb    = xb    + (size_t)400*LC;

    const size_t need = (size_t)1088 * LC * sizeof(bf16);   // ~107 MB
    const bool copy = ws_size >= need;

    if (copy) {
        means_kernel<true><<<dim3((16*LC)/256), dim3(256), 0, stream>>>(
            x, cr, m1x, m1c, m0x, m0c, xb, cb);
        attn_levels_kernel<<<dim3(96), dim3(384), 0, stream>>>(
            m1x, m1c, m0x, m0c, lvl1s, lvl0s);
        attn_full_kernel<bf16><<<dim3(400), dim3(384), 0, stream>>>(
            xb, cb, lvl0s, lvl1s, out);
    } else {
        means_kernel<false><<<dim3((16*LC)/256), dim3(256), 0, stream>>>(
            x, cr, m1x, m1c, m0x, m0c, nullptr, nullptr);
        attn_levels_kernel<<<dim3(96), dim3(384), 0, stream>>>(
            m1x, m1c, m0x, m0c, lvl1s, lvl0s);
        attn_full_kernel<float><<<dim3(400), dim3(384), 0, stream>>>(
            x, cr, lvl0s, lvl1s, out);
    }
}